// Round 1
// baseline (390.256 us; speedup 1.0000x reference)
//
#include <hip/hip_runtime.h>
#include <hip/hip_bf16.h>

// Problem constants (B,S,H,A,D) = (16, 4096, 1024, 1024, 6), all f32.
#define Bn 16
#define Sn 4096
#define Hn 1024
#define An 1024
#define Dn 6
#define TOK_PER_BLK 32           // 32 tokens per block -> 2048 blocks, all same batch
#define NBLOCKS (Bn * Sn / TOK_PER_BLK)

constexpr float LN_EPS_F   = 1e-5f;
constexpr float CLS_SCALE  = 1.0f;

__device__ __forceinline__ float rcp_fast(float x) { return __builtin_amdgcn_rcpf(x); }

__device__ __forceinline__ float fast_sigmoid(float x) {
    return rcp_fast(1.f + __expf(-x));
}

__device__ __forceinline__ float fast_tanh(float x) {
    float ax = fabsf(x);
    float z  = __expf(-2.f * ax);              // in (0,1]
    float t  = (1.f - z) * rcp_fast(1.f + z);
    return copysignf(t, x);
}

__device__ __forceinline__ float gelu_exact(float x) {
    return 0.5f * x * (1.f + erff(x * 0.7071067811865476f));
}

// butterfly sum across the 64-lane wave; every lane ends with the total
__device__ __forceinline__ float wred(float v) {
    #pragma unroll
    for (int m = 1; m < 64; m <<= 1) v += __shfl_xor(v, m, 64);
    return v;
}

__global__ __launch_bounds__(256, 2) void fused_attn_hidden_kernel(
    const float* __restrict__ hidden,
    const float* __restrict__ attn,
    const float* __restrict__ gamma,
    const float* __restrict__ beta,
    const float* __restrict__ Wr,     // [6][1024]
    const float* __restrict__ Wc,     // [6][1024]
    const float* __restrict__ We,     // [1024][6]
    const float* __restrict__ Wtg,    // [1][1024]
    const float* __restrict__ btg,    // [1]
    const float* __restrict__ Wsg,    // [1][6]
    const float* __restrict__ bsg,    // [1]
    const float* __restrict__ lsc,    // [1][1][1024]
    float* __restrict__ out)
{
    __shared__ float WT[7 * An];      // rows 0..5 = Wr, row 6 = Wtg   (28 KB)
    __shared__ float WeT[6 * Hn];     // We transposed [d][h]          (24 KB)
    __shared__ float sc[8];           // sctx[0..5], gate

    const int tid = threadIdx.x;
    const int l   = tid & 63;         // lane in wave
    const int w   = tid >> 6;         // wave id (0..3)

    // ---- stage weights into LDS (coalesced global reads) ----
    for (int i = tid; i < 7 * An; i += 256) {
        int r = i >> 10;
        WT[i] = (r < 6) ? Wr[i] : Wtg[i - 6 * An];
    }
    for (int i = tid; i < Hn * Dn; i += 256) {
        int h = (int)((unsigned)i / 6u);
        int d = i - h * 6;
        WeT[d * Hn + h] = We[i];
    }

    // ---- per-lane invariant vectors (same a/h indices for every token) ----
    float4 g4[4], be4[4], ls4[4];
    #pragma unroll
    for (int e = 0; e < 4; e++) {
        int idx = l + 64 * e;
        g4[e]  = reinterpret_cast<const float4*>(gamma)[idx];
        be4[e] = reinterpret_cast<const float4*>(beta)[idx];
        ls4[e] = reinterpret_cast<const float4*>(lsc)[idx];
    }

    const int  blk = blockIdx.x;
    const int  b   = blk / (Sn / TOK_PER_BLK);
    const long t0  = (long)blk * TOK_PER_BLK;   // global token base (= b*Sn + s0)

    __syncthreads();   // WT/WeT staged

    // ---- wave 0: CLS-token (s=0 of this batch) -> sctx[6], gate ----
    if (w == 0) {
        const float4* arow = reinterpret_cast<const float4*>(attn + (size_t)b * Sn * An);
        float4 x[4];
        #pragma unroll
        for (int e = 0; e < 4; e++) x[e] = arow[l + 64 * e];
        float s = 0.f, ss = 0.f;
        #pragma unroll
        for (int e = 0; e < 4; e++) {
            s  += x[e].x + x[e].y + x[e].z + x[e].w;
            ss += x[e].x * x[e].x + x[e].y * x[e].y + x[e].z * x[e].z + x[e].w * x[e].w;
        }
        #pragma unroll
        for (int m = 1; m < 64; m <<= 1) { s += __shfl_xor(s, m, 64); ss += __shfl_xor(ss, m, 64); }
        float mu   = s * (1.f / An);
        float var  = ss * (1.f / An) - mu * mu;
        float rstd = rsqrtf(var + LN_EPS_F);

        float accr[6] = {}, accc[6] = {};
        #pragma unroll
        for (int e = 0; e < 4; e++) {
            int idx = l + 64 * e;
            float4 a4;
            a4.x = (x[e].x - mu) * rstd * g4[e].x + be4[e].x;
            a4.y = (x[e].y - mu) * rstd * g4[e].y + be4[e].y;
            a4.z = (x[e].z - mu) * rstd * g4[e].z + be4[e].z;
            a4.w = (x[e].w - mu) * rstd * g4[e].w + be4[e].w;
            #pragma unroll
            for (int d = 0; d < 6; d++) {
                float4 wr = reinterpret_cast<const float4*>(WT + d * An)[idx];
                float4 wc = reinterpret_cast<const float4*>(Wc + d * An)[idx];
                accr[d] += a4.x * wr.x + a4.y * wr.y + a4.z * wr.z + a4.w * wr.w;
                accc[d] += a4.x * wc.x + a4.y * wc.y + a4.z * wc.z + a4.w * wc.w;
            }
        }
        float gsum = 0.f;
        float sctx_l[6];
        #pragma unroll
        for (int d = 0; d < 6; d++) {
            float r  = wred(accr[d]);
            float c  = wred(accc[d]);
            float sd = CLS_SCALE * c;
            sctx_l[d] = sd;
            gsum += gelu_exact(r + sd) * Wsg[d];
        }
        float gate = fast_sigmoid(gsum + bsg[0]);
        if (l < 6)  sc[l] = sctx_l[l];
        if (l == 6) sc[6] = gate;
    }
    __syncthreads();

    float sctx[6];
    #pragma unroll
    for (int d = 0; d < 6; d++) sctx[d] = sc[d];
    const float gate = sc[6];
    const float btg0 = btg[0];

    // ---- main loop: one token per wave per iteration ----
    #pragma unroll 1
    for (int it = 0; it < TOK_PER_BLK / 4; ++it) {
        const long t = t0 + w + 4 * it;
        const float4* arow = reinterpret_cast<const float4*>(attn   + (size_t)t * An);
        const float4* hrow = reinterpret_cast<const float4*>(hidden + (size_t)t * Hn);
        float4 x[4], hd[4];
        #pragma unroll
        for (int e = 0; e < 4; e++) x[e]  = arow[l + 64 * e];
        #pragma unroll
        for (int e = 0; e < 4; e++) hd[e] = hrow[l + 64 * e];

        // LN stats
        float s = 0.f, ss = 0.f;
        #pragma unroll
        for (int e = 0; e < 4; e++) {
            s  += x[e].x + x[e].y + x[e].z + x[e].w;
            ss += x[e].x * x[e].x + x[e].y * x[e].y + x[e].z * x[e].z + x[e].w * x[e].w;
        }
        #pragma unroll
        for (int m = 1; m < 64; m <<= 1) { s += __shfl_xor(s, m, 64); ss += __shfl_xor(ss, m, 64); }
        float mu   = s * (1.f / An);
        float var  = ss * (1.f / An) - mu * mu;
        float rstd = rsqrtf(var + LN_EPS_F);

        // 7 dots: Wr rows 0..5 + Wtg
        float acc[7] = {};
        #pragma unroll
        for (int e = 0; e < 4; e++) {
            int idx = l + 64 * e;
            float4 a4;
            a4.x = (x[e].x - mu) * rstd * g4[e].x + be4[e].x;
            a4.y = (x[e].y - mu) * rstd * g4[e].y + be4[e].y;
            a4.z = (x[e].z - mu) * rstd * g4[e].z + be4[e].z;
            a4.w = (x[e].w - mu) * rstd * g4[e].w + be4[e].w;
            #pragma unroll
            for (int d = 0; d < 7; d++) {
                float4 wv = reinterpret_cast<const float4*>(WT + d * An)[idx];
                acc[d] += a4.x * wv.x + a4.y * wv.y + a4.z * wv.z + a4.w * wv.w;
            }
        }
        #pragma unroll
        for (int d = 0; d < 7; d++) acc[d] = wred(acc[d]);

        float th[6];
        #pragma unroll
        for (int d = 0; d < 6; d++) th[d] = gelu_exact(acc[d] + sctx[d]);
        const float tg = fast_sigmoid(acc[6] + btg0);
        const float K  = gate * tg;

        float4* orow = reinterpret_cast<float4*>(out + (size_t)t * Hn);
        #pragma unroll
        for (int e = 0; e < 4; e++) {
            int idx = l + 64 * e;
            float4 w0 = reinterpret_cast<const float4*>(WeT + 0 * Hn)[idx];
            float4 w1 = reinterpret_cast<const float4*>(WeT + 1 * Hn)[idx];
            float4 w2 = reinterpret_cast<const float4*>(WeT + 2 * Hn)[idx];
            float4 w3 = reinterpret_cast<const float4*>(WeT + 3 * Hn)[idx];
            float4 w4 = reinterpret_cast<const float4*>(WeT + 4 * Hn)[idx];
            float4 w5 = reinterpret_cast<const float4*>(WeT + 5 * Hn)[idx];
            float4 mi;
            mi.x = th[0]*w0.x + th[1]*w1.x + th[2]*w2.x + th[3]*w3.x + th[4]*w4.x + th[5]*w5.x;
            mi.y = th[0]*w0.y + th[1]*w1.y + th[2]*w2.y + th[3]*w3.y + th[4]*w4.y + th[5]*w5.y;
            mi.z = th[0]*w0.z + th[1]*w1.z + th[2]*w2.z + th[3]*w3.z + th[4]*w4.z + th[5]*w5.z;
            mi.w = th[0]*w0.w + th[1]*w1.w + th[2]*w2.w + th[3]*w3.w + th[4]*w4.w + th[5]*w5.w;
            float4 hv = hd[e];
            float4 o;
            o.x = hv.x * (1.f + K * ls4[e].x * fast_tanh(mi.x));
            o.y = hv.y * (1.f + K * ls4[e].y * fast_tanh(mi.y));
            o.z = hv.z * (1.f + K * ls4[e].z * fast_tanh(mi.z));
            o.w = hv.w * (1.f + K * ls4[e].w * fast_tanh(mi.w));
            orow[idx] = o;
        }
    }
}

extern "C" void kernel_launch(void* const* d_in, const int* in_sizes, int n_in,
                              void* d_out, int out_size, void* d_ws, size_t ws_size,
                              hipStream_t stream) {
    const float* hidden = (const float*)d_in[0];
    const float* attn   = (const float*)d_in[1];
    const float* gamma  = (const float*)d_in[2];
    const float* beta   = (const float*)d_in[3];
    const float* Wr     = (const float*)d_in[4];
    const float* Wc     = (const float*)d_in[5];
    const float* We     = (const float*)d_in[6];
    const float* Wtg    = (const float*)d_in[7];
    const float* btg    = (const float*)d_in[8];
    const float* Wsg    = (const float*)d_in[9];
    const float* bsg    = (const float*)d_in[10];
    const float* lsc    = (const float*)d_in[11];
    float* out = (float*)d_out;

    fused_attn_hidden_kernel<<<dim3(NBLOCKS), dim3(256), 0, stream>>>(
        hidden, attn, gamma, beta, Wr, Wc, We, Wtg, btg, Wsg, bsg, lsc, out);
}